// Round 17
// baseline (56.484 us; speedup 1.0000x reference)
//
#include <hip/hip_runtime.h>
#include <math.h>

namespace {
constexpr int kB = 128;
constexpr int kV = 128256;
constexpr int kSplits = 64;
constexpr int kSplit = kV / kSplits;   // 2004
constexpr int kSplit4 = kSplit / 4;    // 501 float4
constexpr int kW = 64;                 // block = ONE wave
constexpr int kE = 8;                  // float4 regs/lane: 8*64=512 >= 501
constexpr int kCap = 128;              // candidate cap (2 regs/lane)
constexpr int kTop = 64;               // max top_k
constexpr int kT2 = 1024;              // sample block: 16 waves, tree merge

using f4v = __attribute__((ext_vector_type(4))) float;

// monotonic uint key: ascending key <=> ascending float (finite, non-NaN)
__device__ __forceinline__ unsigned fkey(float y) {
  unsigned u = __float_as_uint(y);
  return ((int)u < 0) ? ~u : (u | 0x80000000u);
}
__device__ __forceinline__ float keyinv(unsigned k) {
  unsigned u = (k & 0x80000000u) ? (k & 0x7fffffffu) : ~k;
  return __uint_as_float(u);
}

// Wave-local LDS fence: all prior ds_writes complete before later ds_reads.
__device__ __forceinline__ void wave_lds_fence() {
  __builtin_amdgcn_sched_barrier(0);
  asm volatile("s_waitcnt lgkmcnt(0)" ::: "memory");
  __builtin_amdgcn_sched_barrier(0);
}

// Merge two sorted-desc 64-runs (b pre-reversed): top-64 multiset, desc.
// Validated absmax-0 in R11/R13/R14/R15/R16.
__device__ __forceinline__ unsigned long long merge_desc(
    unsigned long long v, unsigned long long b, int lane) {
  v = v > b ? v : b;
#pragma unroll
  for (int j = 32; j; j >>= 1) {
    unsigned long long o = __shfl_xor(v, j);
    v = ((lane & j) == 0) ? (v > o ? v : o) : (v < o ? v : o);
  }
  return v;
}

// Full 64-element descending bitonic sort across one wave, in-register.
__device__ __forceinline__ unsigned long long sort64_desc(
    unsigned long long v, int lane) {
#pragma unroll
  for (int k2 = 2; k2 <= 64; k2 <<= 1) {
#pragma unroll
    for (int j = k2 >> 1; j; j >>= 1) {
      unsigned long long o = __shfl_xor(v, j);
      const bool keep_max = (((lane & k2) == 0) == ((lane & j) == 0));
      v = keep_max ? (o > v ? o : v) : (o < v ? o : v);
    }
  }
  return v;
}

// Role-split kernel, one wave per block:
//   bx <  kSplits : SELECT role — R16's one-wave select, READ-ONLY
//                   (no output stores at all).
//   bx >= kSplits : STREAMER role — pure nt-store zero-fill of split
//                   bx-kSplits.
// Reader and writer blocks schedule independently across CUs, overlapping
// the two memory streams without phase coupling.
__global__ __launch_bounds__(kW) void k_work(
    const float* __restrict__ logits, const float* __restrict__ temps,
    float* __restrict__ out,
    float* __restrict__ wm, float* __restrict__ wS,
    unsigned long long* __restrict__ wpk) {
  const int bx = blockIdx.x, row = blockIdx.y;
  const int lane = threadIdx.x;

  if (bx >= kSplits) {
    // ---- streamer role: zero split (bx - kSplits) of this row ----
    const int sp = bx - kSplits;
    f4v* out4 = (f4v*)(out + 2 * kB + (size_t)row * kV + (size_t)sp * kSplit);
    const f4v z4 = {0.f, 0.f, 0.f, 0.f};
#pragma unroll
    for (int e = 0; e < kE; ++e) {
      int f = lane + e * kW;
      if (f < kSplit4) __builtin_nontemporal_store(z4, out4 + f);
    }
    return;
  }

  // ---- select role: byte-identical numerics to R15/R16 (minus zero-fill) ----
  const int sp = bx;
  __shared__ unsigned long long cand[kCap];   // 1 KB, wave-local use only

  const float t = temps[row];
  const float invt = 1.0f / t;
  const size_t rowbase = (size_t)row * kV + (size_t)sp * kSplit;
  const float4* in4 = (const float4*)(logits + rowbase);
  const float nI = -INFINITY;

  float4 r[kE];
  float m = nI;
#pragma unroll
  for (int e = 0; e < kE; ++e) {
    int f = lane + e * kW;
    float4 l;
    if (f < kSplit4) l = in4[f];
    else l = make_float4(nI, nI, nI, nI);
    r[e] = l;
    m = fmaxf(m, fmaxf(fmaxf(l.x, l.y), fmaxf(l.z, l.w)));
  }
  for (int o = 32; o; o >>= 1) m = fmaxf(m, __shfl_xor(m, o));
  const float M = m;          // wave max (order-exact)
  const float My = M / t;     // == max(l/t) bitwise (monotone IEEE div)
  const float negMy = -My;

  float s = 0.f;
#pragma unroll
  for (int e = 0; e < kE; ++e) {
    s += __expf(fmaf(r[e].x, invt, negMy));
    s += __expf(fmaf(r[e].y, invt, negMy));
    s += __expf(fmaf(r[e].z, invt, negMy));
    s += __expf(fmaf(r[e].w, invt, negMy));
  }
  for (int o = 32; o; o >>= 1) s += __shfl_xor(s, o);
  const float Ssp = s;

  unsigned lo = 0x00800000u;
  unsigned hi = fkey(M) + 1;
  for (int it = 0; it < 32 && hi - lo > 1; ++it) {
    unsigned mid = lo + ((hi - lo) >> 1);
    if (it == 0) {
      unsigned p0 = fkey(M - 3.0f);
      if (p0 > lo && p0 < hi) mid = p0;
    } else if (it == 1) {
      unsigned p1 = fkey(M - 4.0f);
      if (p1 > lo && p1 < hi) mid = p1;
    }
    const float mf = keyinv(mid);
    int c = 0;
#pragma unroll
    for (int e = 0; e < kE; ++e) {
      c += (int)__popcll(__ballot(r[e].x >= mf));
      c += (int)__popcll(__ballot(r[e].y >= mf));
      c += (int)__popcll(__ballot(r[e].z >= mf));
      c += (int)__popcll(__ballot(r[e].w >= mf));
    }
    if (c >= kTop) { lo = mid; if (c <= kCap) break; }
    else hi = mid;
  }
  const float Tf = keyinv(lo);

  const unsigned long long lmask = (1ULL << lane) - 1ULL;
  int base = 0;
#pragma unroll
  for (int e = 0; e < kE; ++e) {
    int f = lane + e * kW;
    const float vals[4] = {r[e].x, r[e].y, r[e].z, r[e].w};
#pragma unroll
    for (int j = 0; j < 4; ++j) {
      const float lv = vals[j];
      const bool p = lv >= Tf;
      const unsigned long long mk = __ballot(p);
      if (p) {
        const int pos = base + (int)__popcll(mk & lmask);
        if (pos < kCap)
          cand[pos] = ((unsigned long long)fkey(lv) << 32) |
                      (unsigned)~(unsigned)(sp * kSplit + f * 4 + j);
      }
      base += (int)__popcll(mk);
    }
  }
  const int nc = base < kCap ? base : kCap;
  if (lane >= nc) cand[lane] = 0ULL;
  if (kW + lane >= nc) cand[kW + lane] = 0ULL;
  wave_lds_fence();
  unsigned long long v0 = cand[lane];
  unsigned long long v1 = cand[kW + lane];

  v0 = sort64_desc(v0, lane);
  v1 = sort64_desc(v1, lane);
  v0 = merge_desc(v0, __shfl(v1, 63 - lane), lane);

  wpk[((size_t)row * kSplits + sp) * kTop + lane] = v0;
  if (lane == 0) {
    wm[row * kSplits + sp] = My;
    wS[row * kSplits + sp] = Ssp;
  }
}

// 1024 threads / 16 waves per row: 3-level tree merge of 64 sorted runs,
// then the validated replicated-lane epilogue. Verbatim from R16.
__global__ __launch_bounds__(kT2) void k_sample(
    const float* __restrict__ temps,
    const int* __restrict__ top_ks, const float* __restrict__ top_ps,
    const float* __restrict__ uin,
    const float* __restrict__ wm, const float* __restrict__ wS,
    const unsigned long long* __restrict__ wpk, float* __restrict__ out) {
  const int row = blockIdx.x, tid = threadIdx.x;
  const int lane = tid & 63, wid = tid >> 6;   // 0..15
  __shared__ unsigned long long runs[20 * 64]; // L1: [0..15], L2: [16..19]
  __shared__ float mArr[kSplits], sArr[kSplits];

  if (wid == 15) {              // stage the 64 (M,S) partials
    mArr[lane] = wm[row * kSplits + lane];
    sArr[lane] = wS[row * kSplits + lane];
  }
  const unsigned long long* basek = wpk + (size_t)row * (kSplits * kTop);

  // L1: wave w merges global runs 4w..4w+3 (3 merges, 4 parallel loads).
  unsigned long long mv = basek[(size_t)(4 * wid) * kTop + lane];
#pragma unroll
  for (int s2 = 1; s2 < 4; ++s2) {
    unsigned long long b =
        basek[(size_t)(4 * wid + s2) * kTop + (kTop - 1 - lane)];
    mv = merge_desc(mv, b, lane);
  }
  runs[wid * 64 + lane] = mv;
  __syncthreads();

  // L2: waves 0..3 merge L1 runs 4w..4w+3 -> slots 16+w (disjoint).
  if (wid < 4) {
    mv = runs[(4 * wid) * 64 + lane];
#pragma unroll
    for (int s2 = 1; s2 < 4; ++s2)
      mv = merge_desc(mv, runs[(4 * wid + s2) * 64 + (63 - lane)], lane);
    runs[(16 + wid) * 64 + lane] = mv;
  }
  __syncthreads();
  if (wid != 0) return;

  // L3: wave 0 merges the 4 L2 runs -> row top-64 (lane r = rank r).
  mv = runs[16 * 64 + lane];
#pragma unroll
  for (int s2 = 1; s2 < 4; ++s2)
    mv = merge_desc(mv, runs[(16 + s2) * 64 + (63 - lane)], lane);

  const float tvl = keyinv((unsigned)(mv >> 32)) / temps[row];  // exact l/t
  const int til = (int)(~(unsigned)(mv & 0xffffffffu));

  // fixed-order (M,S) combine, replicated per lane (same order as ref).
  float MM = -INFINITY;
  for (int s2 = 0; s2 < kSplits; ++s2) MM = fmaxf(MM, mArr[s2]);
  float SS = 0.f;
  for (int s2 = 0; s2 < kSplits; ++s2)
    SS += expf(mArr[s2] - MM) * sArr[s2];

  const float tp = top_ps[row];
  const int kk = top_ks[row];
  const float uu = uin[row];

  // reference-order epilogue, replicated across lanes (validated).
  float cum = 0.f, q0 = 0.f, qa_keep = 0.f;
  for (int r2 = 0; r2 < kTop; ++r2) {
    const float tvr = __shfl(tvl, r2);
    const float pr = expf(tvr - MM) / SS;
    cum += pr;
    const float cb = cum - pr;                 // cumulative BEFORE this token
    const float q = ((cb > tp) || (r2 >= kk)) ? 0.f : pr;
    if (r2 == 0) q0 = q;                       // rank 0 never masked
    if (lane == r2) qa_keep = q;
  }
  float tot = 0.f, sv_keep = 0.f, cdf_keep = 0.f;
  for (int r2 = 0; r2 < kTop; ++r2) {
    const float qr = __shfl(qa_keep, r2);
    const float sr = qr / q0;
    tot += sr;
    if (lane == r2) { sv_keep = sr; cdf_keep = tot; }
  }
  const float rth = uu * tot;
  int cnt = (int)__popcll(__ballot(cdf_keep < rth));  // == Σ(cdf < rth)
  if (cnt > kTop - 1) cnt = kTop - 1;
  const int sampled = __shfl(til, cnt);

  if (lane == 0) {
    out[row] = (float)sampled;                 // sampled token id
    out[kB + row] = 1.0f;                      // success
  }
  out[2 * kB + (size_t)row * kV + lane] = sv_keep;  // cols 0..63 (zeroed in k_work)
}
}  // namespace

extern "C" void kernel_launch(void* const* d_in, const int* in_sizes, int n_in,
                              void* d_out, int out_size, void* d_ws, size_t ws_size,
                              hipStream_t stream) {
  const float* logits = (const float*)d_in[0];
  const float* temps  = (const float*)d_in[1];
  const int*   top_ks = (const int*)d_in[2];
  const float* top_ps = (const float*)d_in[3];
  const float* uin    = (const float*)d_in[4];
  float* out = (float*)d_out;

  // workspace layout (~4.3 MB)
  float* wm = (float*)d_ws;                          // [B*Splits] split max (y-space)
  float* wS = wm + kB * kSplits;                     // [B*Splits] split sumexp
  unsigned long long* wpk =                          // [B*Splits*Top] sorted top-64
      (unsigned long long*)(wS + kB * kSplits + kB * kSplits);

  k_work<<<dim3(2 * kSplits, kB), kW, 0, stream>>>(logits, temps, out, wm, wS, wpk);
  k_sample<<<kB, kT2, 0, stream>>>(temps, top_ks, top_ps, uin, wm, wS, wpk, out);
}

// Round 18
// 48.542 us; speedup vs baseline: 1.1636x; 1.1636x over previous
//
#include <hip/hip_runtime.h>
#include <math.h>

namespace {
constexpr int kB = 128;
constexpr int kV = 128256;
constexpr int kSplits = 16;
constexpr int kSplit = kV / kSplits;   // 8016
constexpr int kSplit4 = kSplit / 4;    // 2004 float4
constexpr int kT1 = 256;
constexpr int kE = 8;                  // float4 regs/thread: 8*256=2048 >= 2004
constexpr int kCap = 256;              // candidate cap (== kT1, 1 per thread)
constexpr int kTop = 64;               // max top_k

using f4v = __attribute__((ext_vector_type(4))) float;

// monotonic uint key: ascending key <=> ascending float (finite, non-NaN)
__device__ __forceinline__ unsigned fkey(float y) {
  unsigned u = __float_as_uint(y);
  return ((int)u < 0) ? ~u : (u | 0x80000000u);
}
__device__ __forceinline__ float keyinv(unsigned k) {
  unsigned u = (k & 0x80000000u) ? (k & 0x7fffffffu) : ~k;
  return __uint_as_float(u);
}

// Workgroup barrier waiting on LDS traffic ONLY (not global-store acks).
__device__ __forceinline__ void bar_lds() {
  __builtin_amdgcn_sched_barrier(0);
  asm volatile("s_waitcnt lgkmcnt(0)" ::: "memory");
  __builtin_amdgcn_s_barrier();
  __builtin_amdgcn_sched_barrier(0);
}

// Merge a sorted-desc run held in v (this wave) with sorted-desc run B
// accessed reversed via idx 63-lane: keeps top-64 multiset, restores
// descending order. Validated absmax-0 in R11/R13/R14/R15/R16.
__device__ __forceinline__ unsigned long long merge_desc(
    unsigned long long v, unsigned long long b, int lane) {
  v = v > b ? v : b;
#pragma unroll
  for (int j = 32; j; j >>= 1) {
    unsigned long long o = __shfl_xor(v, j);
    v = ((lane & j) == 0) ? (v > o ? v : o) : (v < o ? v : o);
  }
  return v;
}

__global__ __launch_bounds__(kT1) void k_select(
    const float* __restrict__ logits, const float* __restrict__ temps,
    float* __restrict__ out,
    float* __restrict__ wm, float* __restrict__ wS,
    unsigned long long* __restrict__ wpk) {
  const int sp = blockIdx.x, row = blockIdx.y, tid = threadIdx.x;
  const int lane = tid & 63, wid = tid >> 6;
  __shared__ float wred[4];
  __shared__ float ssum[4];
  __shared__ int cnt2[2][4];
  __shared__ unsigned long long cand[kCap];
  __shared__ int scnt;

  if (tid == 0) scnt = 0;
  const float t = temps[row];
  const float invt = 1.0f / t;
  const size_t rowbase = (size_t)row * kV + (size_t)sp * kSplit;
  const float4* in4 = (const float4*)(logits + rowbase);
  f4v* out4 = (f4v*)(out + 2 * kB + rowbase);
  const float nI = -INFINITY;

  // Load RAW logits into registers (selection order is temperature-
  // invariant: l -> l/t strictly monotone). Loads only before B1.
  float4 r[kE];
  float m = nI;
#pragma unroll
  for (int e = 0; e < kE; ++e) {
    int f = tid + e * kT1;
    float4 l;
    if (f < kSplit4) l = in4[f];
    else l = make_float4(nI, nI, nI, nI);
    r[e] = l;
    m = fmaxf(m, fmaxf(fmaxf(l.x, l.y), fmaxf(l.z, l.w)));
  }
  for (int o = 32; o; o >>= 1) m = fmaxf(m, __shfl_xor(m, o));
  if (lane == 0) wred[wid] = m;
  bar_lds();                                         // B1
  const float M = fmaxf(fmaxf(wred[0], wred[1]), fmaxf(wred[2], wred[3]));
  const float My = M / t;     // == max(l/t) bitwise (monotone IEEE div)
  const float negMy = -My;

  // Zero-fill with nt-stores (no L2 write-allocate); lgkm-only barriers
  // keep the acks off every later phase's critical path.
  {
    const f4v z4 = {0.f, 0.f, 0.f, 0.f};
#pragma unroll
    for (int e = 0; e < kE; ++e) {
      int f = tid + e * kT1;
      if (f < kSplit4) __builtin_nontemporal_store(z4, out4 + f);
    }
  }

  float s = 0.f;
#pragma unroll
  for (int e = 0; e < kE; ++e) {
    s += __expf(fmaf(r[e].x, invt, negMy));
    s += __expf(fmaf(r[e].y, invt, negMy));
    s += __expf(fmaf(r[e].z, invt, negMy));
    s += __expf(fmaf(r[e].w, invt, negMy));
  }
  for (int o = 32; o; o >>= 1) s += __shfl_xor(s, o);
  if (lane == 0) ssum[wid] = s;
  bar_lds();                                         // B2
  const float Ssp = ssum[0] + ssum[1] + ssum[2] + ssum[3];

  // Binary-search threshold T (key space), count(l >= T) in [64,256].
  unsigned lo = 0x00800000u;
  unsigned hi = fkey(M) + 1;
  for (int it = 0; it < 32 && hi - lo > 1; ++it) {
    unsigned mid = lo + ((hi - lo) >> 1);
    if (it == 0) {
      unsigned p0 = fkey(M - 3.0f);
      if (p0 > lo && p0 < hi) mid = p0;
    } else if (it == 1) {
      unsigned p1 = fkey(M - 4.5f);
      if (p1 > lo && p1 < hi) mid = p1;
    }
    const float mf = keyinv(mid);
    int cw = 0;
#pragma unroll
    for (int e = 0; e < kE; ++e) {
      cw += (int)__popcll(__ballot(r[e].x >= mf));
      cw += (int)__popcll(__ballot(r[e].y >= mf));
      cw += (int)__popcll(__ballot(r[e].z >= mf));
      cw += (int)__popcll(__ballot(r[e].w >= mf));
    }
    if (lane == 0) cnt2[it & 1][wid] = cw;
    bar_lds();                                       // B3..
    const int c = cnt2[it & 1][0] + cnt2[it & 1][1] +
                  cnt2[it & 1][2] + cnt2[it & 1][3];
    if (c >= kTop) { lo = mid; if (c <= kCap) break; }
    else hi = mid;
  }
  const float Tf = keyinv(lo);

  // Collect candidates (raw-float compare; fkey only for survivors).
#pragma unroll
  for (int e = 0; e < kE; ++e) {
    int f = tid + e * kT1;
    const float vals[4] = {r[e].x, r[e].y, r[e].z, r[e].w};
#pragma unroll
    for (int j = 0; j < 4; ++j) {
      const float lv = vals[j];
      if (lv >= Tf) {
        int pos = atomicAdd(&scnt, 1);
        if (pos < kCap)
          cand[pos] = ((unsigned long long)fkey(lv) << 32) |
                      (unsigned)~(unsigned)(sp * kSplit + f * 4 + j);
      }
    }
  }
  bar_lds();                                         // B6
  const int nc = scnt < kCap ? scnt : kCap;
  unsigned long long v = (tid < nc) ? cand[tid] : 0ULL;

  // Per-wave 64-element bitonic sort, descending: 21 shfl stages, 0 barriers.
  for (int k2 = 2; k2 <= 64; k2 <<= 1) {
    for (int j = k2 >> 1; j; j >>= 1) {
      unsigned long long o = __shfl_xor(v, j);
      const bool keep_max = (((lane & k2) == 0) == ((lane & j) == 0));
      v = keep_max ? (o > v ? o : v) : (o < v ? o : v);
    }
  }
  cand[tid] = v;           // 4 sorted desc 64-runs (same slot: no hazard)
  bar_lds();               // B7 — last barrier
  if (wid == 0) {          // wave 0 merges 4 runs -> split top-64 sorted
    v = cand[lane];
#pragma unroll
    for (int s2 = 1; s2 < 4; ++s2)
      v = merge_desc(v, cand[s2 * 64 + (63 - lane)], lane);
    wpk[((size_t)row * kSplits + sp) * kTop + lane] = v;
    if (lane == 0) {
      wm[row * kSplits + sp] = My;
      wS[row * kSplits + sp] = Ssp;
    }
  }
}

// 256 threads: 4 waves each merge 4 sorted runs from global (loads issued
// up-front, coalesced), 1 barrier, wave 0 merges 4 -> 1, then the
// R11-validated replicated-lane epilogue with LDS-staged (M,S) combine.
__global__ __launch_bounds__(kT1) void k_sample(
    const float* __restrict__ temps,
    const int* __restrict__ top_ks, const float* __restrict__ top_ps,
    const float* __restrict__ uin,
    const float* __restrict__ wm, const float* __restrict__ wS,
    const unsigned long long* __restrict__ wpk, float* __restrict__ out) {
  const int row = blockIdx.x, tid = threadIdx.x;
  const int lane = tid & 63, wid = tid >> 6;
  __shared__ unsigned long long runs[kT1];   // 4 sorted 64-runs
  __shared__ float mArr[kSplits], sArr[kSplits];

  if (tid >= kT1 - kSplits) {   // wave 3 lanes stage (M,S); others load keys
    const int s2 = tid - (kT1 - kSplits);
    mArr[s2] = wm[row * kSplits + s2];
    sArr[s2] = wS[row * kSplits + s2];
  }
  const unsigned long long* basek = wpk + (size_t)row * (kSplits * kTop);
  unsigned long long mv = basek[(size_t)(4 * wid) * kTop + lane];
#pragma unroll
  for (int s2 = 1; s2 < 4; ++s2) {
    unsigned long long b = basek[(size_t)(4 * wid + s2) * kTop + (kTop - 1 - lane)];
    mv = merge_desc(mv, b, lane);
  }
  runs[tid] = mv;
  __syncthreads();
  if (wid != 0) return;

  mv = runs[lane];
#pragma unroll
  for (int s2 = 1; s2 < 4; ++s2)
    mv = merge_desc(mv, runs[s2 * 64 + (63 - lane)], lane);
  // lane r holds rank-r candidate of the full row.
  const float tvl = keyinv((unsigned)(mv >> 32)) / temps[row];  // exact l/t
  const int til = (int)(~(unsigned)(mv & 0xffffffffu));

  // fixed-order (M,S) combine from LDS, replicated per lane (same op
  // order as the reference merge loop -> bit-identical).
  float MM = -INFINITY;
  for (int s2 = 0; s2 < kSplits; ++s2) MM = fmaxf(MM, mArr[s2]);
  float SS = 0.f;
  for (int s2 = 0; s2 < kSplits; ++s2)
    SS += expf(mArr[s2] - MM) * sArr[s2];

  const float tp = top_ps[row];
  const int kk = top_ks[row];
  const float uu = uin[row];

  // reference-order epilogue, replicated across lanes (R11-validated).
  float cum = 0.f, q0 = 0.f, qa_keep = 0.f;
  for (int r2 = 0; r2 < kTop; ++r2) {
    const float tvr = __shfl(tvl, r2);
    const float pr = expf(tvr - MM) / SS;
    cum += pr;
    const float cb = cum - pr;                 // cumulative BEFORE this token
    const float q = ((cb > tp) || (r2 >= kk)) ? 0.f : pr;
    if (r2 == 0) q0 = q;                       // rank 0 never masked
    if (lane == r2) qa_keep = q;
  }
  float tot = 0.f, sv_keep = 0.f, cdf_keep = 0.f;
  for (int r2 = 0; r2 < kTop; ++r2) {
    const float qr = __shfl(qa_keep, r2);
    const float sr = qr / q0;
    tot += sr;
    if (lane == r2) { sv_keep = sr; cdf_keep = tot; }
  }
  const float rth = uu * tot;
  int cnt = (int)__popcll(__ballot(cdf_keep < rth));  // == Σ(cdf < rth)
  if (cnt > kTop - 1) cnt = kTop - 1;
  const int sampled = __shfl(til, cnt);

  if (lane == 0) {
    out[row] = (float)sampled;                 // sampled token id
    out[kB + row] = 1.0f;                      // success
  }
  out[2 * kB + (size_t)row * kV + lane] = sv_keep;  // cols 0..63 (after zero-fill)
}
}  // namespace

extern "C" void kernel_launch(void* const* d_in, const int* in_sizes, int n_in,
                              void* d_out, int out_size, void* d_ws, size_t ws_size,
                              hipStream_t stream) {
  const float* logits = (const float*)d_in[0];
  const float* temps  = (const float*)d_in[1];
  const int*   top_ks = (const int*)d_in[2];
  const float* top_ps = (const float*)d_in[3];
  const float* uin    = (const float*)d_in[4];
  float* out = (float*)d_out;

  // workspace layout (~1.1 MB)
  float* wm = (float*)d_ws;                          // [B*Splits] split max (y-space)
  float* wS = wm + kB * kSplits;                     // [B*Splits] split sumexp
  unsigned long long* wpk =                          // [B*Splits*Top] sorted top-64
      (unsigned long long*)(wS + kB * kSplits + kB * kSplits);

  k_select<<<dim3(kSplits, kB), kT1, 0, stream>>>(logits, temps, out, wm, wS, wpk);
  k_sample<<<kB, kT1, 0, stream>>>(temps, top_ks, top_ps, uin, wm, wS, wpk, out);
}